// Round 16
// baseline (46.416 us; speedup 1.0000x reference)
//
#include <hip/hip_runtime.h>
#include <math.h>

typedef unsigned short u16;
typedef unsigned int u32;
typedef __attribute__((ext_vector_type(8))) short bf16x8;
typedef __attribute__((ext_vector_type(4))) float f32x4;

// ---------------- bf16 helpers (manual RNE; inputs are finite) ----------------
__device__ __forceinline__ u16 f2bf(float x) {
    u32 b = __builtin_bit_cast(u32, x);
    b += 0x7FFFu + ((b >> 16) & 1u);
    return (u16)(b >> 16);
}
__device__ __forceinline__ float bf2f(u16 u) {
    u32 b = ((u32)u) << 16;
    return __builtin_bit_cast(float, b);
}

// Swizzled tiled plane address, in 16-byte units.
// Plane layout: [row/128][c/64] tiles of 1024 units;
// unit-in-tile = (row&127)*8 + (slot ^ (row&7)), slot = (c&63)>>3.
__device__ __forceinline__ size_t sw_unit(int row, int c, int CC) {
    int slot = (c & 63) >> 3;
    return ((size_t)((row >> 7) * CC + (c >> 6)) << 10)
         + (size_t)((row & 127) << 3) + (size_t)(slot ^ (row & 7));
}

// ---------------------------------------------------------------------------
// prep: activations + weights -> swizzled bf16 HI planes (R11/R12-proven).
// ---------------------------------------------------------------------------
__device__ void prep_x(const float* __restrict__ X, int C, int HW, int bl, int PT,
                       u16* __restrict__ dh) {
    __shared__ float Xt[64][65];
    const int t = threadIdx.x;
    const int pt = bl % PT, ct = bl / PT;
    const int p0 = pt * 64, c0 = ct * 64;
    const int b = p0 / HW, hw0 = p0 % HW;
    #pragma unroll
    for (int i = 0; i < 16; i++) {
        int r = (t >> 6) + i * 4;
        Xt[r][t & 63] = X[(size_t)(b * C + c0 + r) * HW + hw0 + (t & 63)];
    }
    __syncthreads();
    const int CC = C >> 6;
    #pragma unroll
    for (int it = 0; it < 2; it++) {
        int id = t + it * 256;
        int px = id >> 3, sl = id & 7;
        bf16x8 hv;
        #pragma unroll
        for (int j = 0; j < 8; j++)
            hv[j] = (short)f2bf(Xt[sl * 8 + j][px]);
        size_t unit = sw_unit(p0 + px, c0 + sl * 8, CC);
        *(bf16x8*)(dh + unit * 8) = hv;
    }
}

__device__ void prep_w(const float* __restrict__ W, int C, int bl,
                       u16* __restrict__ dh) {
    const int t = threadIdx.x;
    const int ot = bl & 3, cc = bl >> 2;
    const int o0 = ot * 64, c0 = cc * 64;
    const int CC = C >> 6;
    #pragma unroll
    for (int it = 0; it < 2; it++) {
        int id = t + it * 256;
        int ol = id >> 3, sl = id & 7;
        int o = o0 + ol, c = c0 + sl * 8;
        const float* wp = W + (size_t)o * C + c;
        float4 a = *(const float4*)wp;
        float4 b2 = *(const float4*)(wp + 4);
        float xs[8] = {a.x, a.y, a.z, a.w, b2.x, b2.y, b2.z, b2.w};
        bf16x8 hv;
        #pragma unroll
        for (int j = 0; j < 8; j++)
            hv[j] = (short)f2bf(xs[j]);
        size_t unit = sw_unit(o, c, CC);
        *(bf16x8*)(dh + unit * 8) = hv;
    }
}

// W plane offsets (u16 units) inside Whi
#define OFF_WQ 0
#define OFF_WK0 65536
#define OFF_WV0 163840
#define OFF_WK1 262144
#define OFF_WV1 458752
#define OFF_WFUSE 655360

__global__ __launch_bounds__(256) void prep_k(
    const float* __restrict__ query, const float* __restrict__ mem0, const float* __restrict__ mem1,
    const float* __restrict__ Wq, const float* __restrict__ Wk0, const float* __restrict__ Wv0,
    const float* __restrict__ Wk1, const float* __restrict__ Wv1, const float* __restrict__ Wfuse,
    u16* Xq_hi, u16* Xm0_hi, u16* Xm1_hi, u16* Whi)
{
    const int bx = blockIdx.x;
    if (bx < 512)      prep_x(query, 256, 4096, bx,       128, Xq_hi);
    else if (bx < 704) prep_x(mem0,  384, 1024, bx - 512,  32, Xm0_hi);
    else if (bx < 800) prep_x(mem1,  768,  256, bx - 704,   8, Xm1_hi);
    else {
        int r = bx - 800;
        if (r < 16)       prep_w(Wq,    256, r,       Whi + OFF_WQ);
        else if (r < 40)  prep_w(Wk0,   384, r - 16,  Whi + OFF_WK0);
        else if (r < 64)  prep_w(Wv0,   384, r - 40,  Whi + OFF_WV0);
        else if (r < 112) prep_w(Wk1,   768, r - 64,  Whi + OFF_WK1);
        else if (r < 160) prep_w(Wv1,   768, r - 112, Whi + OFF_WV1);
        else              prep_w(Wfuse, 512, r - 160, Whi + OFF_WFUSE);
    }
}

// ---------------------------------------------------------------------------
// 1-term bf16 MFMA GEMM core (proj, R14-proven): D = Ahi·Bhi (+bias).
// Tile 128 rows x 64 cols, 4 waves = 4 row-quarters (32x64 each, acc 2x4).
// ---------------------------------------------------------------------------
__device__ __forceinline__ void gemm_core(
    const u16* __restrict__ Ahi, const u16* __restrict__ Bhi,
    const float* __restrict__ bias, u16* __restrict__ Y,
    int CC, int am, int bn, u16* smem)
{
    const int t = threadIdx.x, lane = t & 63, w = t >> 6;
    const int l15 = lane & 15, kg = lane >> 4;

    f32x4 acc[2][4];
    #pragma unroll
    for (int a = 0; a < 2; a++)
        #pragma unroll
        for (int b2 = 0; b2 < 4; b2++)
            acc[a][b2] = (f32x4){0.f, 0.f, 0.f, 0.f};

    bf16x8 stgA[4], stgB[2];
    {
        const size_t aoff = ((size_t)(am * CC)) << 13;
        const size_t boff = ((((size_t)(bn >> 1) * CC) << 10) + (size_t)(bn & 1) * 512) * 8;
        #pragma unroll
        for (int it = 0; it < 4; it++)
            stgA[it] = *(const bf16x8*)(Ahi + aoff + (size_t)(t + it * 256) * 8);
        #pragma unroll
        for (int it = 0; it < 2; it++)
            stgB[it] = *(const bf16x8*)(Bhi + boff + (size_t)(t + it * 256) * 8);
    }

    for (int ck = 0; ck < CC; ck++) {
        __syncthreads();
        #pragma unroll
        for (int it = 0; it < 4; it++)
            *(bf16x8*)(smem + (size_t)(t + it * 256) * 8) = stgA[it];
        #pragma unroll
        for (int it = 0; it < 2; it++)
            *(bf16x8*)(smem + 8192 + (size_t)(t + it * 256) * 8) = stgB[it];
        __syncthreads();

        {
            const int cn = (ck + 1 < CC) ? ck + 1 : ck;
            const size_t aoff = ((size_t)(am * CC + cn)) << 13;
            const size_t boff = ((((size_t)(bn >> 1) * CC + cn) << 10) + (size_t)(bn & 1) * 512) * 8;
            #pragma unroll
            for (int it = 0; it < 4; it++)
                stgA[it] = *(const bf16x8*)(Ahi + aoff + (size_t)(t + it * 256) * 8);
            #pragma unroll
            for (int it = 0; it < 2; it++)
                stgB[it] = *(const bf16x8*)(Bhi + boff + (size_t)(t + it * 256) * 8);
        }

        #pragma unroll
        for (int kk = 0; kk < 2; kk++) {
            bf16x8 ah[2], bh[4];
            #pragma unroll
            for (int tr = 0; tr < 2; tr++) {
                int row = w * 32 + tr * 16 + l15;
                int off = row * 64 + (((kk * 4 + kg) ^ (row & 7)) << 3);
                ah[tr] = *(const bf16x8*)(smem + off);
            }
            #pragma unroll
            for (int tc = 0; tc < 4; tc++) {
                int row = tc * 16 + l15;
                int off = row * 64 + (((kk * 4 + kg) ^ (row & 7)) << 3);
                bh[tc] = *(const bf16x8*)(smem + 8192 + off);
            }
            #pragma unroll
            for (int tr = 0; tr < 2; tr++)
                #pragma unroll
                for (int tc = 0; tc < 4; tc++)
                    acc[tr][tc] = __builtin_amdgcn_mfma_f32_16x16x32_bf16(ah[tr], bh[tc], acc[tr][tc], 0, 0, 0);
        }
    }

    float bv[4];
    #pragma unroll
    for (int tc = 0; tc < 4; tc++)
        bv[tc] = bias[bn * 64 + tc * 16 + l15];
    #pragma unroll
    for (int tr = 0; tr < 2; tr++) {
        #pragma unroll
        for (int i = 0; i < 4; i++) {
            int rp = am * 128 + w * 32 + tr * 16 + kg * 4 + i;
            u16* yr = Y + (size_t)rp * 256 + bn * 64 + l15;
            #pragma unroll
            for (int tc = 0; tc < 4; tc++)
                yr[tc * 16] = f2bf(acc[tr][tc][i] + bv[tc]);
        }
    }
}

// proj: q / k0 / v0 / k1 / v1 in one 416-block dispatch (1-term bf16)
__global__ __launch_bounds__(256) void projmm_k(
    const u16* __restrict__ Xq_hi, const u16* __restrict__ Xm0_hi,
    const u16* __restrict__ Xm1_hi, const u16* __restrict__ Whi,
    const float* __restrict__ bq, const float* __restrict__ bk0, const float* __restrict__ bv0,
    const float* __restrict__ bk1, const float* __restrict__ bv1,
    u16* qT, u16* k0T, u16* v0T, u16* k1T, u16* v1T)
{
    __shared__ u16 smem[12288];   // 24 KB
    const int bx = blockIdx.x;
    if (bx < 256) {
        gemm_core(Xq_hi, Whi + OFF_WQ, bq, qT, 4, bx >> 2, bx & 3, smem);
    } else if (bx < 320) {
        const int r = bx - 256;
        gemm_core(Xm0_hi, Whi + OFF_WK0, bk0, k0T, 6, r >> 2, r & 3, smem);
    } else if (bx < 384) {
        const int r = bx - 320;
        gemm_core(Xm0_hi, Whi + OFF_WV0, bv0, v0T, 6, r >> 2, r & 3, smem);
    } else if (bx < 400) {
        const int r = bx - 384;
        gemm_core(Xm1_hi, Whi + OFF_WK1, bk1, k1T, 12, r >> 2, r & 3, smem);
    } else {
        const int r = bx - 400;
        gemm_core(Xm1_hi, Whi + OFF_WV1, bv1, v1T, 12, r >> 2, r & 3, smem);
    }
}

// ---------------------------------------------------------------------------
// fuse GEMM (1-term, R12-proven): out[o][p] = Whi_fuse[o]·fused[p] + bfuse.
// ---------------------------------------------------------------------------
__global__ __launch_bounds__(256) void fusemm_k(
    const u16* __restrict__ Whi, const u16* __restrict__ fhi,
    const float* __restrict__ bias, float* __restrict__ out)
{
    __shared__ u16 smem[12288];
    const int t = threadIdx.x, lane = t & 63, w = t >> 6;
    const int wr = w >> 1, wc = w & 1;
    const int l15 = lane & 15;
    const int am = blockIdx.x & 3, bn = blockIdx.x >> 2;
    const u16* A = Whi + OFF_WFUSE;

    f32x4 acc[2][4];
    #pragma unroll
    for (int a = 0; a < 2; a++)
        #pragma unroll
        for (int b2 = 0; b2 < 4; b2++)
            acc[a][b2] = (f32x4){0.f, 0.f, 0.f, 0.f};

    bf16x8 stgA[2], stgB[4];
    {
        const size_t aoff = (((size_t)(am >> 1) * 8) << 10) + (size_t)(am & 1) * 512;
        const size_t boff = ((size_t)(bn * 8)) << 10;
        #pragma unroll
        for (int it = 0; it < 2; it++)
            stgA[it] = *(const bf16x8*)(A + (aoff + t + it * 256) * 8);
        #pragma unroll
        for (int it = 0; it < 4; it++)
            stgB[it] = *(const bf16x8*)(fhi + (boff + t + it * 256) * 8);
    }

    for (int ck = 0; ck < 8; ck++) {
        __syncthreads();
        #pragma unroll
        for (int it = 0; it < 2; it++)
            *(bf16x8*)(smem + (size_t)(t + it * 256) * 8) = stgA[it];
        #pragma unroll
        for (int it = 0; it < 4; it++)
            *(bf16x8*)(smem + 4096 + (size_t)(t + it * 256) * 8) = stgB[it];
        __syncthreads();

        {
            const int cn = (ck + 1 < 8) ? ck + 1 : ck;
            const size_t aoff = (((size_t)(am >> 1) * 8 + cn) << 10) + (size_t)(am & 1) * 512;
            const size_t boff = ((size_t)(bn * 8 + cn)) << 10;
            #pragma unroll
            for (int it = 0; it < 2; it++)
                stgA[it] = *(const bf16x8*)(A + (aoff + t + it * 256) * 8);
            #pragma unroll
            for (int it = 0; it < 4; it++)
                stgB[it] = *(const bf16x8*)(fhi + (boff + t + it * 256) * 8);
        }

        #pragma unroll
        for (int kk = 0; kk < 2; kk++) {
            bf16x8 ah[2], bh[4];
            #pragma unroll
            for (int tr = 0; tr < 2; tr++) {
                int row = wr * 32 + tr * 16 + l15;
                int off = row * 64 + (((kk * 4 + (lane >> 4)) ^ (row & 7)) << 3);
                ah[tr] = *(const bf16x8*)(smem + off);
            }
            #pragma unroll
            for (int tc = 0; tc < 4; tc++) {
                int row = wc * 64 + tc * 16 + l15;
                int off = row * 64 + (((kk * 4 + (lane >> 4)) ^ (row & 7)) << 3);
                bh[tc] = *(const bf16x8*)(smem + 4096 + off);
            }
            #pragma unroll
            for (int tr = 0; tr < 2; tr++)
                #pragma unroll
                for (int tc = 0; tc < 4; tc++)
                    acc[tr][tc] = __builtin_amdgcn_mfma_f32_16x16x32_bf16(ah[tr], bh[tc], acc[tr][tc], 0, 0, 0);
        }
    }

    #pragma unroll
    for (int tr = 0; tr < 2; tr++) {
        #pragma unroll
        for (int i = 0; i < 4; i++) {
            const int o = am * 64 + wr * 32 + tr * 16 + ((lane >> 4) << 2) + i;
            const float bv = bias[o];
            #pragma unroll
            for (int tc = 0; tc < 4; tc++) {
                const int pcol = bn * 128 + wc * 64 + tc * 16 + l15;
                out[(size_t)((pcol >> 12) * 256 + o) * 4096 + (pcol & 4095)] = acc[tr][tc][i] + bv;
            }
        }
    }
}

// ---------------------------------------------------------------------------
// MFMA attention, block-cooperative K/V staging. One block = (b, head, 8x8
// q-region); the candidate superset of all 4 waves' windows is a 10x10
// coarse frame, staged once into LDS (K+V, 12.8 KB). Per-wave math is
// R14-identical except kf/vf come from LDS. Values staged = old clamped
// global reads -> outputs bit-identical.
//   scale0: frame rows my0 = gy*4-3 .. +9;  fy = sy*2 + wy  (wy of 8x8)
//   scale1: frame rows my0 = gy*2-4 .. +9;  fy = sy + (wy-2)*2 + 4, clamped
//           to 9 for the always-masked wy==5 slots (P=0 exactly).
// ---------------------------------------------------------------------------
template<int SCALE>
__device__ __forceinline__ void attn_core(
    const u16* __restrict__ qT, const u16* __restrict__ sK,
    const u16* __restrict__ sV, u16* __restrict__ fhi,
    int b, int n, int gy, int gx, int sy, int sx, int lane, u16* s_lds)
{
    constexpr int HM = SCALE ? 16 : 32;
    constexpr int NT = SCALE ? 2 : 4;
    const int qy0 = gy * 8 + sy * 4, qx0 = gx * 8 + sx * 4;
    const int ay0 = SCALE ? (gy * 2 + sy) : (gy * 4 + sy * 2);
    const int ax0 = SCALE ? (gx * 2 + sx) : (gx * 4 + sx * 2);
    const int l15 = lane & 15, kg = lane >> 4;

    const int pA = (b * 64 + qy0 + (l15 >> 2)) * 64 + qx0 + (l15 & 3);
    const bf16x8 qf = *(const bf16x8*)(qT + (size_t)pA * 256 + n * 32 + kg * 8);

    f32x4 s[NT];
    #pragma unroll
    for (int t = 0; t < NT; t++) {
        const int cand = t * 16 + l15;
        const int wy = SCALE ? (cand / 6) : (cand >> 3);
        const int wx = SCALE ? (cand % 6) : (cand & 7);
        const int fy = min(SCALE ? (sy + (wy - 2) * 2 + 4) : (sy * 2 + wy), 9);
        const int fx = min(SCALE ? (sx + (wx - 2) * 2 + 4) : (sx * 2 + wx), 9);
        const bf16x8 kf = *(const bf16x8*)(sK + (fy * 10 + fx) * 32 + kg * 8);
        s[t] = __builtin_amdgcn_mfma_f32_16x16x32_bf16(qf, kf, (f32x4){0.f, 0.f, 0.f, 0.f}, 0, 0, 0);
    }

    const float scl = 0.17677669529663687f;
    float sv[NT][4];
    #pragma unroll
    for (int t = 0; t < NT; t++) {
        const int cand = t * 16 + l15;
        const int wy = SCALE ? (cand / 6) : (cand >> 3);
        const int wx = SCALE ? (cand % 6) : (cand & 7);
        const int my = SCALE ? (ay0 + (wy - 2) * 2) : (ay0 - 3 + wy);
        const int mx = SCALE ? (ax0 + (wx - 2) * 2) : (ax0 - 3 + wx);
        const bool inb = (my >= 0) && (my < HM) && (mx >= 0) && (mx < HM);
        #pragma unroll
        for (int i = 0; i < 4; i++) {
            bool ok;
            if (SCALE) {
                ok = inb && (wy < 5) && (wx < 5);
            } else {
                const int r = kg * 4 + i;
                const int dy2 = (r >> 2) >> 1, dx2 = (r & 3) >> 1;
                ok = inb && ((u32)(wy - dy2) <= 6u) && ((u32)(wx - dx2) <= 6u);
            }
            sv[t][i] = ok ? s[t][i] * scl : -1e30f;
        }
    }

    float linv[4];
    #pragma unroll
    for (int i = 0; i < 4; i++) {
        float m = sv[0][i];
        #pragma unroll
        for (int t = 1; t < NT; t++) m = fmaxf(m, sv[t][i]);
        #pragma unroll
        for (int dd = 1; dd < 16; dd <<= 1) m = fmaxf(m, __shfl_xor(m, dd, 64));
        float l = 0.f;
        #pragma unroll
        for (int t = 0; t < NT; t++) { sv[t][i] = __expf(sv[t][i] - m); l += sv[t][i]; }
        #pragma unroll
        for (int dd = 1; dd < 16; dd <<= 1) l += __shfl_xor(l, dd, 64);
        linv[i] = 1.f / l;
    }

    // P -> private LDS slice (no barrier: intra-wave lgkmcnt ordering)
    #pragma unroll
    for (int t = 0; t < NT; t++)
        #pragma unroll
        for (int i = 0; i < 4; i++)
            s_lds[(kg * 4 + i) * 68 + t * 16 + l15] = f2bf(sv[t][i]);

    f32x4 o[2] = {(f32x4){0.f,0.f,0.f,0.f}, (f32x4){0.f,0.f,0.f,0.f}};
    #pragma unroll
    for (int h = 0; h < NT / 2; h++) {
        const bf16x8 pa = *(const bf16x8*)(s_lds + l15 * 68 + h * 32 + kg * 8);
        #pragma unroll
        for (int c = 0; c < 2; c++) {
            bf16x8 vf;
            #pragma unroll
            for (int j = 0; j < 8; j++) {
                const int cand = h * 32 + kg * 8 + j;
                const int wy = SCALE ? (cand / 6) : (cand >> 3);
                const int wx = SCALE ? (cand % 6) : (cand & 7);
                const int fy = min(SCALE ? (sy + (wy - 2) * 2 + 4) : (sy * 2 + wy), 9);
                const int fx = min(SCALE ? (sx + (wx - 2) * 2 + 4) : (sx * 2 + wx), 9);
                vf[j] = (short)sV[(fy * 10 + fx) * 32 + c * 16 + l15];
            }
            o[c] = __builtin_amdgcn_mfma_f32_16x16x32_bf16(pa, vf, o[c], 0, 0, 0);
        }
    }

    #pragma unroll
    for (int c = 0; c < 2; c++) {
        #pragma unroll
        for (int i = 0; i < 4; i++) {
            const int r = kg * 4 + i;
            const int p = (b * 64 + qy0 + (r >> 2)) * 64 + qx0 + (r & 3);
            const int ch = (SCALE ? 256 : 0) + n * 32 + c * 16 + l15;
            fhi[sw_unit(p, ch, 8) * 8 + (ch & 7)] = f2bf(o[c][i] * linv[i]);
        }
    }
}

__global__ __launch_bounds__(256) void attn_k(
    const u16* __restrict__ qT,
    const u16* __restrict__ k0T, const u16* __restrict__ v0T,
    const u16* __restrict__ k1T, const u16* __restrict__ v1T,
    u16* __restrict__ fhi)
{
    __shared__ u16 sK[3200];            // 10x10 frame x 32 ch
    __shared__ u16 sV[3200];
    __shared__ u16 s_lds[4][16 * 68];   // per-wave P slices
    const int t = threadIdx.x, w = t >> 6, lane = t & 63;
    const int bx = blockIdx.x;
    const int sc = bx >> 10;            // 0: scale0, 1: scale1
    const int r = bx & 1023;
    const int b = r >> 9, n = (r >> 6) & 7;
    const int gy = (r >> 3) & 7, gx = r & 7;

    // ---- cooperative frame staging (both planes), then one barrier ----
    {
        const u16* kT = sc ? k1T : k0T;
        const u16* vT = sc ? v1T : v0T;
        const int HM  = sc ? 16 : 32;
        const int my0 = sc ? (gy * 2 - 4) : (gy * 4 - 3);
        const int mx0 = sc ? (gx * 2 - 4) : (gx * 4 - 3);
        #pragma unroll
        for (int p = 0; p < 2; p++) {
            const int idx = t + p * 256;
            if (idx < 400) {
                const int px = idx >> 2, seg = idx & 3;
                const int fy = px / 10, fx = px % 10;
                const int ry = min(max(my0 + fy, 0), HM - 1);
                const int rx = min(max(mx0 + fx, 0), HM - 1);
                const size_t src = (size_t)((b * HM + ry) * HM + rx) * 256 + n * 32 + seg * 8;
                *(bf16x8*)(sK + px * 32 + seg * 8) = *(const bf16x8*)(kT + src);
                *(bf16x8*)(sV + px * 32 + seg * 8) = *(const bf16x8*)(vT + src);
            }
        }
    }
    __syncthreads();

    const int sy = w >> 1, sx = w & 1;
    if (sc == 0) attn_core<0>(qT, sK, sV, fhi, b, n, gy, gx, sy, sx, lane, s_lds[w]);
    else         attn_core<1>(qT, sK, sV, fhi, b, n, gy, gx, sy, sx, lane, s_lds[w]);
}

// ---------------------------------------------------------------------------
extern "C" void kernel_launch(void* const* d_in, const int* in_sizes, int n_in,
                              void* d_out, int out_size, void* d_ws, size_t ws_size,
                              hipStream_t stream)
{
    const float* query = (const float*)d_in[0];
    const float* mem0  = (const float*)d_in[1];
    const float* mem1  = (const float*)d_in[2];
    const float* Wq    = (const float*)d_in[3];  const float* bq    = (const float*)d_in[4];
    const float* Wk0   = (const float*)d_in[5];  const float* bk0   = (const float*)d_in[6];
    const float* Wv0   = (const float*)d_in[7];  const float* bv0   = (const float*)d_in[8];
    const float* Wk1   = (const float*)d_in[9];  const float* bk1   = (const float*)d_in[10];
    const float* Wv1   = (const float*)d_in[11]; const float* bv1   = (const float*)d_in[12];
    const float* Wfuse = (const float*)d_in[13]; const float* bfuse = (const float*)d_in[14];
    float* out = (float*)d_out;

    char* ws = (char*)d_ws;
    u16* qT       = (u16*)(ws + 0);            // 4 MB (bf16 pixel-major)
    u16* k0T      = (u16*)(ws + 8388608);      // 1 MB
    u16* v0T      = (u16*)(ws + 10485760);     // 1 MB
    u16* k1T      = (u16*)(ws + 12582912);     // 256 KB
    u16* v1T      = (u16*)(ws + 13107200);     // 256 KB
    u16* Whi      = (u16*)(ws + 13631488);     // 1.5 MB
    u16* Xm0_hi   = (u16*)(ws + 16777216);     // 1.5 MB
    u16* Xm1_hi   = (u16*)(ws + 19922944);     // 768 KB
    u16* Xq_hi    = (u16*)(ws + 21495808);     // 4 MB
    u16* fhi      = Xq_hi;                     // fused plane (8 MB: Xq_hi + next 4 MB)

    prep_k<<<dim3(992), 256, 0, stream>>>(
        query, mem0, mem1, Wq, Wk0, Wv0, Wk1, Wv1, Wfuse,
        Xq_hi, Xm0_hi, Xm1_hi, Whi);

    projmm_k<<<dim3(416), 256, 0, stream>>>(
        Xq_hi, Xm0_hi, Xm1_hi, Whi,
        bq, bk0, bv0, bk1, bv1, qT, k0T, v0T, k1T, v1T);

    attn_k<<<dim3(2048), 256, 0, stream>>>(qT, k0T, v0T, k1T, v1T, fhi);

    fusemm_k<<<dim3(256), 256, 0, stream>>>(Whi, fhi, bfuse, out);
}

// Round 17
// 45.399 us; speedup vs baseline: 1.0224x; 1.0224x over previous
//
#include <hip/hip_runtime.h>
#include <math.h>

typedef unsigned short u16;
typedef unsigned int u32;
typedef __attribute__((ext_vector_type(8))) short bf16x8;
typedef __attribute__((ext_vector_type(4))) float f32x4;

// ---------------- bf16 helpers (manual RNE; inputs are finite) ----------------
__device__ __forceinline__ u16 f2bf(float x) {
    u32 b = __builtin_bit_cast(u32, x);
    b += 0x7FFFu + ((b >> 16) & 1u);
    return (u16)(b >> 16);
}
__device__ __forceinline__ float bf2f(u16 u) {
    u32 b = ((u32)u) << 16;
    return __builtin_bit_cast(float, b);
}

// Swizzled tiled plane address, in 16-byte units.
// Plane layout: [row/128][c/64] tiles of 1024 units;
// unit-in-tile = (row&127)*8 + (slot ^ (row&7)), slot = (c&63)>>3.
__device__ __forceinline__ size_t sw_unit(int row, int c, int CC) {
    int slot = (c & 63) >> 3;
    return ((size_t)((row >> 7) * CC + (c >> 6)) << 10)
         + (size_t)((row & 127) << 3) + (size_t)(slot ^ (row & 7));
}

// ---------------------------------------------------------------------------
// prep: activations + weights -> swizzled bf16 HI planes (R11/R12-proven).
// ---------------------------------------------------------------------------
__device__ void prep_x(const float* __restrict__ X, int C, int HW, int bl, int PT,
                       u16* __restrict__ dh) {
    __shared__ float Xt[64][65];
    const int t = threadIdx.x;
    const int pt = bl % PT, ct = bl / PT;
    const int p0 = pt * 64, c0 = ct * 64;
    const int b = p0 / HW, hw0 = p0 % HW;
    #pragma unroll
    for (int i = 0; i < 16; i++) {
        int r = (t >> 6) + i * 4;
        Xt[r][t & 63] = X[(size_t)(b * C + c0 + r) * HW + hw0 + (t & 63)];
    }
    __syncthreads();
    const int CC = C >> 6;
    #pragma unroll
    for (int it = 0; it < 2; it++) {
        int id = t + it * 256;
        int px = id >> 3, sl = id & 7;
        bf16x8 hv;
        #pragma unroll
        for (int j = 0; j < 8; j++)
            hv[j] = (short)f2bf(Xt[sl * 8 + j][px]);
        size_t unit = sw_unit(p0 + px, c0 + sl * 8, CC);
        *(bf16x8*)(dh + unit * 8) = hv;
    }
}

__device__ void prep_w(const float* __restrict__ W, int C, int bl,
                       u16* __restrict__ dh) {
    const int t = threadIdx.x;
    const int ot = bl & 3, cc = bl >> 2;
    const int o0 = ot * 64, c0 = cc * 64;
    const int CC = C >> 6;
    #pragma unroll
    for (int it = 0; it < 2; it++) {
        int id = t + it * 256;
        int ol = id >> 3, sl = id & 7;
        int o = o0 + ol, c = c0 + sl * 8;
        const float* wp = W + (size_t)o * C + c;
        float4 a = *(const float4*)wp;
        float4 b2 = *(const float4*)(wp + 4);
        float xs[8] = {a.x, a.y, a.z, a.w, b2.x, b2.y, b2.z, b2.w};
        bf16x8 hv;
        #pragma unroll
        for (int j = 0; j < 8; j++)
            hv[j] = (short)f2bf(xs[j]);
        size_t unit = sw_unit(o, c, CC);
        *(bf16x8*)(dh + unit * 8) = hv;
    }
}

// W plane offsets (u16 units) inside Whi
#define OFF_WQ 0
#define OFF_WK0 65536
#define OFF_WV0 163840
#define OFF_WK1 262144
#define OFF_WV1 458752
#define OFF_WFUSE 655360

__global__ __launch_bounds__(256) void prep_k(
    const float* __restrict__ query, const float* __restrict__ mem0, const float* __restrict__ mem1,
    const float* __restrict__ Wq, const float* __restrict__ Wk0, const float* __restrict__ Wv0,
    const float* __restrict__ Wk1, const float* __restrict__ Wv1, const float* __restrict__ Wfuse,
    u16* Xq_hi, u16* Xm0_hi, u16* Xm1_hi, u16* Whi)
{
    const int bx = blockIdx.x;
    if (bx < 512)      prep_x(query, 256, 4096, bx,       128, Xq_hi);
    else if (bx < 704) prep_x(mem0,  384, 1024, bx - 512,  32, Xm0_hi);
    else if (bx < 800) prep_x(mem1,  768,  256, bx - 704,   8, Xm1_hi);
    else {
        int r = bx - 800;
        if (r < 16)       prep_w(Wq,    256, r,       Whi + OFF_WQ);
        else if (r < 40)  prep_w(Wk0,   384, r - 16,  Whi + OFF_WK0);
        else if (r < 64)  prep_w(Wv0,   384, r - 40,  Whi + OFF_WV0);
        else if (r < 112) prep_w(Wk1,   768, r - 64,  Whi + OFF_WK1);
        else if (r < 160) prep_w(Wv1,   768, r - 112, Whi + OFF_WV1);
        else              prep_w(Wfuse, 512, r - 160, Whi + OFF_WFUSE);
    }
}

// ---------------------------------------------------------------------------
// 1-term bf16 MFMA GEMM core (proj, R14-proven): D = Ahi·Bhi (+bias).
// Tile 128 rows x 64 cols, 4 waves = 4 row-quarters (32x64 each, acc 2x4).
// ---------------------------------------------------------------------------
__device__ __forceinline__ void gemm_core(
    const u16* __restrict__ Ahi, const u16* __restrict__ Bhi,
    const float* __restrict__ bias, u16* __restrict__ Y,
    int CC, int am, int bn, u16* smem)
{
    const int t = threadIdx.x, lane = t & 63, w = t >> 6;
    const int l15 = lane & 15, kg = lane >> 4;

    f32x4 acc[2][4];
    #pragma unroll
    for (int a = 0; a < 2; a++)
        #pragma unroll
        for (int b2 = 0; b2 < 4; b2++)
            acc[a][b2] = (f32x4){0.f, 0.f, 0.f, 0.f};

    bf16x8 stgA[4], stgB[2];
    {
        const size_t aoff = ((size_t)(am * CC)) << 13;
        const size_t boff = ((((size_t)(bn >> 1) * CC) << 10) + (size_t)(bn & 1) * 512) * 8;
        #pragma unroll
        for (int it = 0; it < 4; it++)
            stgA[it] = *(const bf16x8*)(Ahi + aoff + (size_t)(t + it * 256) * 8);
        #pragma unroll
        for (int it = 0; it < 2; it++)
            stgB[it] = *(const bf16x8*)(Bhi + boff + (size_t)(t + it * 256) * 8);
    }

    for (int ck = 0; ck < CC; ck++) {
        __syncthreads();
        #pragma unroll
        for (int it = 0; it < 4; it++)
            *(bf16x8*)(smem + (size_t)(t + it * 256) * 8) = stgA[it];
        #pragma unroll
        for (int it = 0; it < 2; it++)
            *(bf16x8*)(smem + 8192 + (size_t)(t + it * 256) * 8) = stgB[it];
        __syncthreads();

        {
            const int cn = (ck + 1 < CC) ? ck + 1 : ck;
            const size_t aoff = ((size_t)(am * CC + cn)) << 13;
            const size_t boff = ((((size_t)(bn >> 1) * CC + cn) << 10) + (size_t)(bn & 1) * 512) * 8;
            #pragma unroll
            for (int it = 0; it < 4; it++)
                stgA[it] = *(const bf16x8*)(Ahi + aoff + (size_t)(t + it * 256) * 8);
            #pragma unroll
            for (int it = 0; it < 2; it++)
                stgB[it] = *(const bf16x8*)(Bhi + boff + (size_t)(t + it * 256) * 8);
        }

        #pragma unroll
        for (int kk = 0; kk < 2; kk++) {
            bf16x8 ah[2], bh[4];
            #pragma unroll
            for (int tr = 0; tr < 2; tr++) {
                int row = w * 32 + tr * 16 + l15;
                int off = row * 64 + (((kk * 4 + kg) ^ (row & 7)) << 3);
                ah[tr] = *(const bf16x8*)(smem + off);
            }
            #pragma unroll
            for (int tc = 0; tc < 4; tc++) {
                int row = tc * 16 + l15;
                int off = row * 64 + (((kk * 4 + kg) ^ (row & 7)) << 3);
                bh[tc] = *(const bf16x8*)(smem + 8192 + off);
            }
            #pragma unroll
            for (int tr = 0; tr < 2; tr++)
                #pragma unroll
                for (int tc = 0; tc < 4; tc++)
                    acc[tr][tc] = __builtin_amdgcn_mfma_f32_16x16x32_bf16(ah[tr], bh[tc], acc[tr][tc], 0, 0, 0);
        }
    }

    float bv[4];
    #pragma unroll
    for (int tc = 0; tc < 4; tc++)
        bv[tc] = bias[bn * 64 + tc * 16 + l15];
    #pragma unroll
    for (int tr = 0; tr < 2; tr++) {
        #pragma unroll
        for (int i = 0; i < 4; i++) {
            int rp = am * 128 + w * 32 + tr * 16 + kg * 4 + i;
            u16* yr = Y + (size_t)rp * 256 + bn * 64 + l15;
            #pragma unroll
            for (int tc = 0; tc < 4; tc++)
                yr[tc * 16] = f2bf(acc[tr][tc][i] + bv[tc]);
        }
    }
}

// proj: q / k0 / v0 / k1 / v1 in one 416-block dispatch (1-term bf16)
__global__ __launch_bounds__(256) void projmm_k(
    const u16* __restrict__ Xq_hi, const u16* __restrict__ Xm0_hi,
    const u16* __restrict__ Xm1_hi, const u16* __restrict__ Whi,
    const float* __restrict__ bq, const float* __restrict__ bk0, const float* __restrict__ bv0,
    const float* __restrict__ bk1, const float* __restrict__ bv1,
    u16* qT, u16* k0T, u16* v0T, u16* k1T, u16* v1T)
{
    __shared__ u16 smem[12288];   // 24 KB
    const int bx = blockIdx.x;
    if (bx < 256) {
        gemm_core(Xq_hi, Whi + OFF_WQ, bq, qT, 4, bx >> 2, bx & 3, smem);
    } else if (bx < 320) {
        const int r = bx - 256;
        gemm_core(Xm0_hi, Whi + OFF_WK0, bk0, k0T, 6, r >> 2, r & 3, smem);
    } else if (bx < 384) {
        const int r = bx - 320;
        gemm_core(Xm0_hi, Whi + OFF_WV0, bv0, v0T, 6, r >> 2, r & 3, smem);
    } else if (bx < 400) {
        const int r = bx - 384;
        gemm_core(Xm1_hi, Whi + OFF_WK1, bk1, k1T, 12, r >> 2, r & 3, smem);
    } else {
        const int r = bx - 400;
        gemm_core(Xm1_hi, Whi + OFF_WV1, bv1, v1T, 12, r >> 2, r & 3, smem);
    }
}

// ---------------------------------------------------------------------------
// fuse GEMM (1-term, R12-proven): out[o][p] = Whi_fuse[o]·fused[p] + bfuse.
// ---------------------------------------------------------------------------
__global__ __launch_bounds__(256) void fusemm_k(
    const u16* __restrict__ Whi, const u16* __restrict__ fhi,
    const float* __restrict__ bias, float* __restrict__ out)
{
    __shared__ u16 smem[12288];
    const int t = threadIdx.x, lane = t & 63, w = t >> 6;
    const int wr = w >> 1, wc = w & 1;
    const int l15 = lane & 15;
    const int am = blockIdx.x & 3, bn = blockIdx.x >> 2;
    const u16* A = Whi + OFF_WFUSE;

    f32x4 acc[2][4];
    #pragma unroll
    for (int a = 0; a < 2; a++)
        #pragma unroll
        for (int b2 = 0; b2 < 4; b2++)
            acc[a][b2] = (f32x4){0.f, 0.f, 0.f, 0.f};

    bf16x8 stgA[2], stgB[4];
    {
        const size_t aoff = (((size_t)(am >> 1) * 8) << 10) + (size_t)(am & 1) * 512;
        const size_t boff = ((size_t)(bn * 8)) << 10;
        #pragma unroll
        for (int it = 0; it < 2; it++)
            stgA[it] = *(const bf16x8*)(A + (aoff + t + it * 256) * 8);
        #pragma unroll
        for (int it = 0; it < 4; it++)
            stgB[it] = *(const bf16x8*)(fhi + (boff + t + it * 256) * 8);
    }

    for (int ck = 0; ck < 8; ck++) {
        __syncthreads();
        #pragma unroll
        for (int it = 0; it < 2; it++)
            *(bf16x8*)(smem + (size_t)(t + it * 256) * 8) = stgA[it];
        #pragma unroll
        for (int it = 0; it < 4; it++)
            *(bf16x8*)(smem + 4096 + (size_t)(t + it * 256) * 8) = stgB[it];
        __syncthreads();

        {
            const int cn = (ck + 1 < 8) ? ck + 1 : ck;
            const size_t aoff = (((size_t)(am >> 1) * 8 + cn) << 10) + (size_t)(am & 1) * 512;
            const size_t boff = ((size_t)(bn * 8 + cn)) << 10;
            #pragma unroll
            for (int it = 0; it < 2; it++)
                stgA[it] = *(const bf16x8*)(A + (aoff + t + it * 256) * 8);
            #pragma unroll
            for (int it = 0; it < 4; it++)
                stgB[it] = *(const bf16x8*)(fhi + (boff + t + it * 256) * 8);
        }

        #pragma unroll
        for (int kk = 0; kk < 2; kk++) {
            bf16x8 ah[2], bh[4];
            #pragma unroll
            for (int tr = 0; tr < 2; tr++) {
                int row = wr * 32 + tr * 16 + l15;
                int off = row * 64 + (((kk * 4 + (lane >> 4)) ^ (row & 7)) << 3);
                ah[tr] = *(const bf16x8*)(smem + off);
            }
            #pragma unroll
            for (int tc = 0; tc < 4; tc++) {
                int row = wc * 64 + tc * 16 + l15;
                int off = row * 64 + (((kk * 4 + (lane >> 4)) ^ (row & 7)) << 3);
                bh[tc] = *(const bf16x8*)(smem + 4096 + off);
            }
            #pragma unroll
            for (int tr = 0; tr < 2; tr++)
                #pragma unroll
                for (int tc = 0; tc < 4; tc++)
                    acc[tr][tc] = __builtin_amdgcn_mfma_f32_16x16x32_bf16(ah[tr], bh[tc], acc[tr][tc], 0, 0, 0);
        }
    }

    #pragma unroll
    for (int tr = 0; tr < 2; tr++) {
        #pragma unroll
        for (int i = 0; i < 4; i++) {
            const int o = am * 64 + wr * 32 + tr * 16 + ((lane >> 4) << 2) + i;
            const float bv = bias[o];
            #pragma unroll
            for (int tc = 0; tc < 4; tc++) {
                const int pcol = bn * 128 + wc * 64 + tc * 16 + l15;
                out[(size_t)((pcol >> 12) * 256 + o) * 4096 + (pcol & 4095)] = acc[tr][tc][i] + bv;
            }
        }
    }
}

// ---------------------------------------------------------------------------
// MFMA attention (R14 math; global clamped V-gather — R15 staging reverted).
// New epilogue: O transposed through per-wave LDS slice, then ONE bf16x8
// store per lane (full 64B-line coverage) instead of 8 scattered u16 stores.
// Values pass through LDS verbatim -> outputs bit-identical to R14.
// ---------------------------------------------------------------------------
template<int SCALE>
__device__ __forceinline__ void attn_mfma(
    const u16* __restrict__ qT, const u16* __restrict__ kT,
    const u16* __restrict__ vT, u16* __restrict__ fhi,
    int b, int n, int ty, int tx, int lane, u16* s_lds, u16* s_ot)
{
    constexpr int HM = SCALE ? 16 : 32;
    constexpr int NT = SCALE ? 2 : 4;      // 16-cand tiles
    const int qy0 = ty * 4, qx0 = tx * 4;
    const int ay0 = SCALE ? (qy0 >> 2) : (qy0 >> 1);
    const int ax0 = SCALE ? (qx0 >> 2) : (qx0 >> 1);
    const int l15 = lane & 15, kg = lane >> 4;

    const int pA = (b * 64 + qy0 + (l15 >> 2)) * 64 + qx0 + (l15 & 3);
    const bf16x8 qf = *(const bf16x8*)(qT + (size_t)pA * 256 + n * 32 + kg * 8);

    f32x4 s[NT];
    #pragma unroll
    for (int t = 0; t < NT; t++) {
        const int cand = t * 16 + l15;
        const int wy = SCALE ? (cand / 6) : (cand >> 3);
        const int wx = SCALE ? (cand % 6) : (cand & 7);
        const int my = SCALE ? (ay0 + (wy - 2) * 2) : (ay0 - 3 + wy);
        const int mx = SCALE ? (ax0 + (wx - 2) * 2) : (ax0 - 3 + wx);
        const int myc = min(max(my, 0), HM - 1), mxc = min(max(mx, 0), HM - 1);
        const bf16x8 kf = *(const bf16x8*)(kT + (size_t)((b * HM + myc) * HM + mxc) * 256 + n * 32 + kg * 8);
        s[t] = __builtin_amdgcn_mfma_f32_16x16x32_bf16(qf, kf, (f32x4){0.f, 0.f, 0.f, 0.f}, 0, 0, 0);
    }

    const float scl = 0.17677669529663687f;
    float sv[NT][4];
    #pragma unroll
    for (int t = 0; t < NT; t++) {
        const int cand = t * 16 + l15;
        const int wy = SCALE ? (cand / 6) : (cand >> 3);
        const int wx = SCALE ? (cand % 6) : (cand & 7);
        const int my = SCALE ? (ay0 + (wy - 2) * 2) : (ay0 - 3 + wy);
        const int mx = SCALE ? (ax0 + (wx - 2) * 2) : (ax0 - 3 + wx);
        const bool inb = (my >= 0) && (my < HM) && (mx >= 0) && (mx < HM);
        #pragma unroll
        for (int i = 0; i < 4; i++) {
            bool ok;
            if (SCALE) {
                ok = inb && (wy < 5) && (wx < 5);
            } else {
                const int r = kg * 4 + i;
                const int dy2 = (r >> 2) >> 1, dx2 = (r & 3) >> 1;
                ok = inb && ((u32)(wy - dy2) <= 6u) && ((u32)(wx - dx2) <= 6u);
            }
            sv[t][i] = ok ? s[t][i] * scl : -1e30f;
        }
    }

    float linv[4];
    #pragma unroll
    for (int i = 0; i < 4; i++) {
        float m = sv[0][i];
        #pragma unroll
        for (int t = 1; t < NT; t++) m = fmaxf(m, sv[t][i]);
        #pragma unroll
        for (int dd = 1; dd < 16; dd <<= 1) m = fmaxf(m, __shfl_xor(m, dd, 64));
        float l = 0.f;
        #pragma unroll
        for (int t = 0; t < NT; t++) { sv[t][i] = __expf(sv[t][i] - m); l += sv[t][i]; }
        #pragma unroll
        for (int dd = 1; dd < 16; dd <<= 1) l += __shfl_xor(l, dd, 64);
        linv[i] = 1.f / l;
    }

    // P -> private LDS slice (no barrier: intra-wave lgkmcnt ordering)
    #pragma unroll
    for (int t = 0; t < NT; t++)
        #pragma unroll
        for (int i = 0; i < 4; i++)
            s_lds[(kg * 4 + i) * 68 + t * 16 + l15] = f2bf(sv[t][i]);

    f32x4 o[2] = {(f32x4){0.f,0.f,0.f,0.f}, (f32x4){0.f,0.f,0.f,0.f}};
    #pragma unroll
    for (int h = 0; h < NT / 2; h++) {
        const bf16x8 pa = *(const bf16x8*)(s_lds + l15 * 68 + h * 32 + kg * 8);
        #pragma unroll
        for (int c = 0; c < 2; c++) {
            bf16x8 vf;
            #pragma unroll
            for (int j = 0; j < 8; j++) {
                const int cand = h * 32 + kg * 8 + j;
                const int wy = SCALE ? (cand / 6) : (cand >> 3);
                const int wx = SCALE ? (cand % 6) : (cand & 7);
                int my = SCALE ? (ay0 + (wy - 2) * 2) : (ay0 - 3 + wy);
                int mx = SCALE ? (ax0 + (wx - 2) * 2) : (ax0 - 3 + wx);
                my = min(max(my, 0), HM - 1); mx = min(max(mx, 0), HM - 1);
                vf[j] = (short)vT[(size_t)((b * HM + my) * HM + mx) * 256 + n * 32 + c * 16 + l15];
            }
            o[c] = __builtin_amdgcn_mfma_f32_16x16x32_bf16(pa, vf, o[c], 0, 0, 0);
        }
    }

    // ---- transpose O through LDS (stride 34 breaks kg-stride conflicts),
    //      then one contiguous bf16x8 store per lane ----
    #pragma unroll
    for (int c = 0; c < 2; c++)
        #pragma unroll
        for (int i = 0; i < 4; i++)
            s_ot[(kg * 4 + i) * 34 + c * 16 + l15] = f2bf(o[c][i] * linv[i]);

    {
        const int rl = lane >> 2;          // pixel 0..15 within tile
        const int cs = lane & 3;           // 8-channel segment 0..3
        const bf16x8 ov = *(const bf16x8*)(s_ot + rl * 34 + cs * 8);
        const int p = (b * 64 + qy0 + (rl >> 2)) * 64 + qx0 + (rl & 3);
        const int ch0 = (SCALE ? 256 : 0) + n * 32 + cs * 8;
        *(bf16x8*)(fhi + sw_unit(p, ch0, 8) * 8) = ov;
    }
}

__global__ __launch_bounds__(256) void attn_k(
    const u16* __restrict__ qT,
    const u16* __restrict__ k0T, const u16* __restrict__ v0T,
    const u16* __restrict__ k1T, const u16* __restrict__ v1T,
    u16* __restrict__ fhi)
{
    __shared__ u16 s_lds[4][16 * 68];
    __shared__ u16 s_ot[4][16 * 34];
    const int t = threadIdx.x, w = t >> 6, lane = t & 63;
    const int bx = blockIdx.x;
    const int sc = bx >> 10;
    const int tile = (bx & 1023) * 4 + w;
    const int b = tile >> 11, n = (tile >> 8) & 7;
    const int ty = (tile >> 4) & 15, tx = tile & 15;
    if (sc == 0) attn_mfma<0>(qT, k0T, v0T, fhi, b, n, ty, tx, lane, s_lds[w], s_ot[w]);
    else         attn_mfma<1>(qT, k1T, v1T, fhi, b, n, ty, tx, lane, s_lds[w], s_ot[w]);
}

// ---------------------------------------------------------------------------
extern "C" void kernel_launch(void* const* d_in, const int* in_sizes, int n_in,
                              void* d_out, int out_size, void* d_ws, size_t ws_size,
                              hipStream_t stream)
{
    const float* query = (const float*)d_in[0];
    const float* mem0  = (const float*)d_in[1];
    const float* mem1  = (const float*)d_in[2];
    const float* Wq    = (const float*)d_in[3];  const float* bq    = (const float*)d_in[4];
    const float* Wk0   = (const float*)d_in[5];  const float* bk0   = (const float*)d_in[6];
    const float* Wv0   = (const float*)d_in[7];  const float* bv0   = (const float*)d_in[8];
    const float* Wk1   = (const float*)d_in[9];  const float* bk1   = (const float*)d_in[10];
    const float* Wv1   = (const float*)d_in[11]; const float* bv1   = (const float*)d_in[12];
    const float* Wfuse = (const float*)d_in[13]; const float* bfuse = (const float*)d_in[14];
    float* out = (float*)d_out;

    char* ws = (char*)d_ws;
    u16* qT       = (u16*)(ws + 0);            // 4 MB (bf16 pixel-major)
    u16* k0T      = (u16*)(ws + 8388608);      // 1 MB
    u16* v0T      = (u16*)(ws + 10485760);     // 1 MB
    u16* k1T      = (u16*)(ws + 12582912);     // 256 KB
    u16* v1T      = (u16*)(ws + 13107200);     // 256 KB
    u16* Whi      = (u16*)(ws + 13631488);     // 1.5 MB
    u16* Xm0_hi   = (u16*)(ws + 16777216);     // 1.5 MB
    u16* Xm1_hi   = (u16*)(ws + 19922944);     // 768 KB
    u16* Xq_hi    = (u16*)(ws + 21495808);     // 4 MB
    u16* fhi      = Xq_hi;                     // fused plane (8 MB: Xq_hi + next 4 MB)

    prep_k<<<dim3(992), 256, 0, stream>>>(
        query, mem0, mem1, Wq, Wk0, Wv0, Wk1, Wv1, Wfuse,
        Xq_hi, Xm0_hi, Xm1_hi, Whi);

    projmm_k<<<dim3(416), 256, 0, stream>>>(
        Xq_hi, Xm0_hi, Xm1_hi, Whi,
        bq, bk0, bv0, bk1, bv1, qT, k0T, v0T, k1T, v1T);

    attn_k<<<dim3(2048), 256, 0, stream>>>(qT, k0T, v0T, k1T, v1T, fhi);

    fusemm_k<<<dim3(256), 256, 0, stream>>>(Whi, fhi, bfuse, out);
}